// Round 6
// baseline (489.988 us; speedup 1.0000x reference)
//
#include <hip/hip_runtime.h>
#include <hip/hip_bf16.h>

typedef short bf16x8 __attribute__((ext_vector_type(8)));
typedef float f32x4 __attribute__((ext_vector_type(4)));
typedef unsigned short u16;

#define LOG2E 1.44269504088896340736f

__device__ __forceinline__ u16 f2bf(float f) {
    unsigned u = __float_as_uint(f);
    u += 0x7fffu + ((u >> 16) & 1u);   // round-to-nearest-even
    return (u16)(u >> 16);
}
__device__ __forceinline__ float bf2f(u16 h) {
    return __uint_as_float(((unsigned)h) << 16);
}

// ---------------------------------------------------------------------------
// Kernel 0: weight prep. Combined rows: [0,256)=Wv, [256,288)=Wq*log2e, [288,320)=Wk.
// Split each f32 weight into bf16 hi + bf16 lo. Combined bias (q-bias pre-scaled).
// ---------------------------------------------------------------------------
__global__ void k_prep(const float* __restrict__ Wq, const float* __restrict__ bq,
                       const float* __restrict__ Wk, const float* __restrict__ bk,
                       const float* __restrict__ Wv, const float* __restrict__ bv,
                       u16* __restrict__ Whi, u16* __restrict__ Wlo,
                       float* __restrict__ bias) {
    int idx = blockIdx.x * 256 + threadIdx.x;
    if (idx >= 320 * 256) return;
    int row = idx >> 8, c = idx & 255;
    float w, b;
    if (row < 256)      { w = Wv[row * 256 + c];                  b = bv[row]; }
    else if (row < 288) { w = Wq[(row - 256) * 256 + c] * LOG2E;  b = bq[row - 256] * LOG2E; }
    else                { w = Wk[(row - 288) * 256 + c];          b = bk[row - 288]; }
    u16 hi = f2bf(w);
    Whi[idx] = hi;
    Wlo[idx] = f2bf(w - bf2f(hi));
    if (c == 0) bias[row] = b;
}

// ---------------------------------------------------------------------------
// Kernel 1: fused QKV projection. out[320 rows][4096 n] per batch via MFMA.
// 3-term split product: Whi*xhi + Whi*xlo + Wlo*xhi  (~fp32 accuracy).
// Writes: vbf[b][256][4096] bf16 ; qt/kt[b][4096][64] bf16 (cols 0..31 hi, 32..63 lo)
// ---------------------------------------------------------------------------
#define XPAD 264  // xT row stride in elems (=528B, 16B-multiple, conflict-friendly)

__global__ __launch_bounds__(256) void k_proj(
    const float* __restrict__ x, const u16* __restrict__ Whi,
    const u16* __restrict__ Wlo, const float* __restrict__ bias,
    u16* __restrict__ qt, u16* __restrict__ kt, u16* __restrict__ vbf) {
    __shared__ __attribute__((aligned(16))) u16 xh[64 * XPAD];
    __shared__ __attribute__((aligned(16))) u16 xl[64 * XPAD];
    int bid = blockIdx.x;
    int b = bid & 7, nt = bid >> 3;
    int n0 = nt * 64;
    int t = threadIdx.x;
    int lane = t & 63, w = t >> 6;
    int lr = lane & 15, lk = lane >> 4;

    // ---- stage x tile transposed + bf16-split into LDS ----
    {
        int n = t & 63;
        int cg = t >> 6;
        for (int it = 0; it < 8; ++it) {
            int c8 = (it * 4 + cg) * 8;
            bf16x8 hv, lv;
#pragma unroll
            for (int u = 0; u < 8; ++u) {
                float xv = x[((size_t)(b * 256 + c8 + u)) * 4096 + n0 + n];
                u16 hu = f2bf(xv);
                hv[u] = (short)hu;
                lv[u] = (short)f2bf(xv - bf2f(hu));
            }
            *(bf16x8*)&xh[n * XPAD + c8] = hv;
            *(bf16x8*)&xl[n * XPAD + c8] = lv;
        }
    }
    __syncthreads();

    f32x4 acc[5][4];
#pragma unroll
    for (int i = 0; i < 5; i++)
#pragma unroll
        for (int j = 0; j < 4; j++) acc[i][j] = (f32x4){0.f, 0.f, 0.f, 0.f};

    for (int cs = 0; cs < 8; ++cs) {
        int c0 = cs * 32;
        bf16x8 ah[5], al[5], bh[4], bl[4];
#pragma unroll
        for (int mt = 0; mt < 5; ++mt) {
            int row = (w * 5 + mt) * 16 + lr;
            ah[mt] = *(const bf16x8*)&Whi[row * 256 + c0 + lk * 8];
            al[mt] = *(const bf16x8*)&Wlo[row * 256 + c0 + lk * 8];
        }
#pragma unroll
        for (int ns = 0; ns < 4; ++ns) {
            int np = ns * 16 + lr;
            bh[ns] = *(const bf16x8*)&xh[np * XPAD + c0 + lk * 8];
            bl[ns] = *(const bf16x8*)&xl[np * XPAD + c0 + lk * 8];
        }
#pragma unroll
        for (int mt = 0; mt < 5; ++mt)
#pragma unroll
            for (int ns = 0; ns < 4; ++ns) {
                acc[mt][ns] = __builtin_amdgcn_mfma_f32_16x16x32_bf16(ah[mt], bh[ns], acc[mt][ns], 0, 0, 0);
                acc[mt][ns] = __builtin_amdgcn_mfma_f32_16x16x32_bf16(ah[mt], bl[ns], acc[mt][ns], 0, 0, 0);
                acc[mt][ns] = __builtin_amdgcn_mfma_f32_16x16x32_bf16(al[mt], bh[ns], acc[mt][ns], 0, 0, 0);
            }
    }

    // ---- epilogue: bias + scatter to v / q(hi,lo) / k(hi,lo) ----
#pragma unroll
    for (int mt = 0; mt < 5; ++mt) {
        int tile = w * 5 + mt;  // 0..19 ; 16-row tiles never straddle v/q/k regions
#pragma unroll
        for (int ns = 0; ns < 4; ++ns) {
#pragma unroll
            for (int r = 0; r < 4; ++r) {
                int row = tile * 16 + lk * 4 + r;
                int n = n0 + ns * 16 + lr;
                float val = acc[mt][ns][r] + bias[row];
                if (row < 256) {
                    vbf[((size_t)(b * 256 + row)) * 4096 + n] = f2bf(val);
                } else if (row < 288) {
                    u16 hi = f2bf(val);
                    size_t base = ((size_t)(b * 4096 + n)) * 64 + (row - 256);
                    qt[base] = hi;
                    qt[base + 32] = f2bf(val - bf2f(hi));
                } else {
                    u16 hi = f2bf(val);
                    size_t base = ((size_t)(b * 4096 + n)) * 64 + (row - 288);
                    kt[base] = hi;
                    kt[base + 32] = f2bf(val - bf2f(hi));
                }
            }
        }
    }
}

// ---------------------------------------------------------------------------
// Kernel 1.5: softmax statistics pass. For every column j: M[b][j] = max_i s,
// L[b][j] = sum_i exp2(s - M). Per-lane online state only (lane owns column
// jw+lr, i-subset lk); cross-lane combine ONCE at the end. No barriers.
// ---------------------------------------------------------------------------
__global__ __launch_bounds__(256, 2) void k_ml(
    const u16* __restrict__ qt, const u16* __restrict__ kt,
    float* __restrict__ Mg, float* __restrict__ Lg) {
    int bid = blockIdx.x;
    int b = bid & 7, jt = bid >> 3;
    int t = threadIdx.x;
    int lane = t & 63, w = t >> 6;
    int lr = lane & 15, lk = lane >> 4;
    int jw = jt * 64 + w * 16;

    size_t kb = ((size_t)(b * 4096 + jw + lr)) * 64 + lk * 8;
    bf16x8 khi = *(const bf16x8*)&kt[kb];
    bf16x8 klo = *(const bf16x8*)&kt[kb + 32];
    const f32x4 zero = {0.f, 0.f, 0.f, 0.f};

    float m = -3.0e38f, sum = 0.f;
    for (int it = 0; it < 64; ++it) {
        int i0 = it * 64;
        bf16x8 qh[4], ql[4];
#pragma unroll
        for (int g = 0; g < 4; ++g) {
            size_t qb = ((size_t)(b * 4096 + i0 + g * 16 + lr)) * 64 + lk * 8;
            qh[g] = *(const bf16x8*)&qt[qb];
            ql[g] = *(const bf16x8*)&qt[qb + 32];
        }
        f32x4 s[4];
#pragma unroll
        for (int g = 0; g < 4; ++g) {
            s[g] = __builtin_amdgcn_mfma_f32_16x16x32_bf16(qh[g], khi, zero, 0, 0, 0);
            s[g] = __builtin_amdgcn_mfma_f32_16x16x32_bf16(qh[g], klo, s[g], 0, 0, 0);
            s[g] = __builtin_amdgcn_mfma_f32_16x16x32_bf16(ql[g], khi, s[g], 0, 0, 0);
        }
        float tm = -3.0e38f;
#pragma unroll
        for (int g = 0; g < 4; ++g)
            tm = fmaxf(tm, fmaxf(fmaxf(s[g][0], s[g][1]), fmaxf(s[g][2], s[g][3])));
        float mnew = fmaxf(m, tm);
        sum *= exp2f(m - mnew);   // exp2(-huge)=0 on first iter: sum stays 0
        m = mnew;
#pragma unroll
        for (int g = 0; g < 4; ++g) {
            sum += exp2f(s[g][0] - m) + exp2f(s[g][1] - m)
                 + exp2f(s[g][2] - m) + exp2f(s[g][3] - m);
        }
    }
    // combine the 4 lanes (lk=0..3) holding the same column
#pragma unroll
    for (int d = 16; d <= 32; d <<= 1) {
        float pm = __shfl_xor(m, d), ps = __shfl_xor(sum, d);
        float m2 = fmaxf(m, pm);
        sum = sum * exp2f(m - m2) + ps * exp2f(pm - m2);
        m = m2;
    }
    if (lane < 16) {
        Mg[b * 4096 + jw + lr] = m;
        Lg[b * 4096 + jw + lr] = sum;
    }
}

// ---------------------------------------------------------------------------
// Kernel 2: attention as a pure tiled GEMM with on-the-fly P (two-pass).
// P[i][j] = exp2(s[i][j] - M[j])  (<=1 by construction; no rescale, no shfl,
// no cross-iteration state). Block = 64 j-cols, 4 waves; wave w computes the
// P-subtile for j-sub w AND PVs c-chunk w*64. Double-buffered P, ONE barrier
// per 64-i tile. q prefetched one step ahead (reg double-buffer); av issued
// pre-barrier (the barrier's vmcnt drain completes them); q-next issued
// post-barrier, covered by the 32 PV MFMAs. Output f32.
// ---------------------------------------------------------------------------
#define PSTR 72  // P row stride in u16: 64 i + pad; 144B rows (16B-aligned)

__global__ __launch_bounds__(256, 2) void k_attn(
    const u16* __restrict__ qt, const u16* __restrict__ kt,
    const u16* __restrict__ vbf, const float* __restrict__ Mg,
    const float* __restrict__ Lg, const float* __restrict__ x,
    const float* __restrict__ gamma, float* __restrict__ out) {
    __shared__ __attribute__((aligned(16))) u16 P[2][4][16][PSTR];  // 18.4 KB
    int bid = blockIdx.x;
    int b = bid & 7, jt = bid >> 3;  // b = bid%8 pins batch -> XCD (L2 locality)
    int t = threadIdx.x;
    int lane = t & 63, w = t >> 6;
    int lr = lane & 15, lk = lane >> 4;
    int j0 = jt * 64, jw = j0 + w * 16;

    size_t kb = ((size_t)(b * 4096 + jw + lr)) * 64 + lk * 8;
    bf16x8 khi = *(const bf16x8*)&kt[kb];
    bf16x8 klo = *(const bf16x8*)&kt[kb + 32];
    float mcol = Mg[b * 4096 + jw + lr];   // column max for this lane's P column

    f32x4 acc[4][4];
#pragma unroll
    for (int i = 0; i < 4; i++)
#pragma unroll
        for (int j = 0; j < 4; j++) acc[i][j] = (f32x4){0.f, 0.f, 0.f, 0.f};
    const f32x4 zero = {0.f, 0.f, 0.f, 0.f};

    // one pipeline step: QK(q_cur) -> P[p] -> av loads -> barrier -> q_next
    // loads (covered by PV) -> PV(av, P[p]).
    auto step = [&](int p, int itc, bf16x8 (&qh)[4], bf16x8 (&ql)[4],
                    bf16x8 (&qhn)[4], bf16x8 (&qln)[4]) {
        int i0 = itc * 64;
        // QK^T (3-term split) for 64 i-rows of own 16 cols
        f32x4 s[4];
#pragma unroll
        for (int g = 0; g < 4; ++g) {
            s[g] = __builtin_amdgcn_mfma_f32_16x16x32_bf16(qh[g], khi, zero, 0, 0, 0);
            s[g] = __builtin_amdgcn_mfma_f32_16x16x32_bf16(qh[g], klo, s[g], 0, 0, 0);
            s[g] = __builtin_amdgcn_mfma_f32_16x16x32_bf16(ql[g], khi, s[g], 0, 0, 0);
        }
        // P = exp2(s - M) ; pack to bf16 ; write own subtile
#pragma unroll
        for (int g = 0; g < 4; ++g) {
            float p0 = exp2f(s[g][0] - mcol), p1 = exp2f(s[g][1] - mcol);
            float p2 = exp2f(s[g][2] - mcol), p3 = exp2f(s[g][3] - mcol);
            uint2 pk;
            pk.x = ((unsigned)f2bf(p1) << 16) | f2bf(p0);
            pk.y = ((unsigned)f2bf(p3) << 16) | f2bf(p2);
            *(uint2*)&P[p][w][lr][g * 16 + lk * 4] = pk;
        }
        // v loads for THIS step (drained by the barrier's vmcnt wait)
        bf16x8 av[8];
#pragma unroll
        for (int ks = 0; ks < 2; ++ks)
#pragma unroll
            for (int ct = 0; ct < 4; ++ct)
                av[ks * 4 + ct] = *(const bf16x8*)&vbf[((size_t)(b * 256 + w * 64 + ct * 16 + lr)) * 4096
                                                       + i0 + ks * 32 + lk * 8];
        __syncthreads();   // publishes P[p]; drains av loads
        // q prefetch for next step (latency covered by PV below)
        int i0n = ((itc + 1) & 63) * 64;   // wraps 64->0: harmless reload
#pragma unroll
        for (int g = 0; g < 4; ++g) {
            size_t qb = ((size_t)(b * 4096 + i0n + g * 16 + lr)) * 64 + lk * 8;
            qhn[g] = *(const bf16x8*)&qt[qb];
            qln[g] = *(const bf16x8*)&qt[qb + 32];
        }
        // PV: acc[c, j] += v[c, i-tile] * P[i-tile, j]
#pragma unroll
        for (int ks = 0; ks < 2; ++ks) {
            bf16x8 bp[4];
#pragma unroll
            for (int js = 0; js < 4; ++js)
                bp[js] = *(const bf16x8*)&P[p][js][lr][ks * 32 + lk * 8];
#pragma unroll
            for (int ct = 0; ct < 4; ++ct)
#pragma unroll
                for (int js = 0; js < 4; ++js)
                    acc[ct][js] = __builtin_amdgcn_mfma_f32_16x16x32_bf16(av[ks * 4 + ct], bp[js], acc[ct][js], 0, 0, 0);
        }
    };

    // prologue: load q for it=0
    bf16x8 qhA[4], qlA[4], qhB[4], qlB[4];
#pragma unroll
    for (int g = 0; g < 4; ++g) {
        size_t qb = ((size_t)(b * 4096 + g * 16 + lr)) * 64 + lk * 8;
        qhA[g] = *(const bf16x8*)&qt[qb];
        qlA[g] = *(const bf16x8*)&qt[qb + 32];
    }
    for (int it = 0; it < 64; it += 2) {
        step(0, it,     qhA, qlA, qhB, qlB);
        step(1, it + 1, qhB, qlB, qhA, qlA);
    }

    // ---- epilogue: per-column 1/L from global; f32 output ----
    float g = gamma[0];
    float linv[4];
#pragma unroll
    for (int js = 0; js < 4; ++js) linv[js] = g / Lg[b * 4096 + j0 + js * 16 + lr];
#pragma unroll
    for (int ct = 0; ct < 4; ++ct)
#pragma unroll
        for (int r = 0; r < 4; ++r) {
            int c = w * 64 + ct * 16 + lk * 4 + r;
            size_t base = ((size_t)(b * 256 + c)) * 4096 + j0;
#pragma unroll
            for (int js = 0; js < 4; ++js) {
                int j = js * 16 + lr;
                out[base + j] = acc[ct][js][r] * linv[js] + x[base + j];
            }
        }
}

// ---------------------------------------------------------------------------
extern "C" void kernel_launch(void* const* d_in, const int* in_sizes, int n_in,
                              void* d_out, int out_size, void* d_ws, size_t ws_size,
                              hipStream_t stream) {
    const float* x = (const float*)d_in[0];
    const float* Wq = (const float*)d_in[1];
    const float* bq = (const float*)d_in[2];
    const float* Wk = (const float*)d_in[3];
    const float* bk = (const float*)d_in[4];
    const float* Wv = (const float*)d_in[5];
    const float* bv = (const float*)d_in[6];
    const float* gamma = (const float*)d_in[7];

    char* ws = (char*)d_ws;
    u16* Whi = (u16*)ws;                               // 163840 B
    u16* Wlo = (u16*)(ws + 163840);                    // 163840 B
    float* bias = (float*)(ws + 327680);               // 1280 B
    u16* qt = (u16*)(ws + 329216);                     // 4 MB  [8][4096][64]
    u16* kt = (u16*)(ws + 329216 + 4194304);           // 4 MB
    u16* vbf = (u16*)(ws + 329216 + 8388608);          // 16 MB [8][256][4096]
    float* Mg = (float*)(ws + 329216 + 25165824);      // 128 KB [8][4096]
    float* Lg = (float*)(ws + 329216 + 25165824 + 131072);  // 128 KB
    // total ws use ~25.8 MB

    k_prep<<<320, 256, 0, stream>>>(Wq, bq, Wk, bk, Wv, bv, Whi, Wlo, bias);
    k_proj<<<512, 256, 0, stream>>>(x, Whi, Wlo, bias, qt, kt, vbf);
    k_ml<<<512, 256, 0, stream>>>(qt, kt, Mg, Lg);
    k_attn<<<512, 256, 0, stream>>>(qt, kt, vbf, Mg, Lg, x, gamma, (float*)d_out);
}